// Round 2
// baseline (89.728 us; speedup 1.0000x reference)
//
#include <hip/hip_runtime.h>
#include <math.h>

// ---------------------------------------------------------------------------
// PrefrontalCortex: memory-augmented LSTM cell, batch=1, fp32.
// All matmuls are GEMVs -> memory-bound. 12 kernels in dependency order.
// R2: gates GEMV split into two gemv64 dispatches (the fused/unrolled version
// compiled to VGPR=16 and ran latency-serialized at 1.3 TB/s).
// ---------------------------------------------------------------------------

#define INPUT_DIM 2048
#define HIDDEN_DIM 2048
#define MEM_SLOTS 4096
#define MEM_DIM 1024
#define OUTPUT_DIM 2048

static __device__ __forceinline__ float sigmoidf_(float x) {
    return 1.0f / (1.0f + expf(-x));
}

// Generic wave-per-row GEMV: out[r] = act(dot(W[r,:], v) + bias[r])
// k4 = K/4 (row length in float4). act: 0 = none, 1 = tanh.
// Proven ~5-6 TB/s effective on this problem (R1 counters).
__global__ void gemv64_kernel(const float* __restrict__ W, const float* __restrict__ v,
                              const float* __restrict__ bias, float* __restrict__ out,
                              int rows, int k4, int act) {
    int wave = (int)((blockIdx.x * blockDim.x + threadIdx.x) >> 6);
    int lane = threadIdx.x & 63;
    if (wave >= rows) return;
    const float4* Wr = (const float4*)W + (size_t)wave * (size_t)k4;
    const float4* v4 = (const float4*)v;
    float acc = 0.f;
    for (int i = lane; i < k4; i += 64) {
        float4 w4 = Wr[i];
        float4 x4 = v4[i];
        acc = fmaf(w4.x, x4.x, acc);
        acc = fmaf(w4.y, x4.y, acc);
        acc = fmaf(w4.z, x4.z, acc);
        acc = fmaf(w4.w, x4.w, acc);
    }
#pragma unroll
    for (int off = 32; off > 0; off >>= 1) acc += __shfl_down(acc, off);
    if (lane == 0) {
        float r = acc + (bias ? bias[wave] : 0.f);
        if (act == 1) r = tanhf(r);
        out[wave] = r;
    }
}

// softmax over sim[0:4096] -> rw; usage_out = usage + rw.  One block, 1024 thr.
__global__ void softmax_rw_kernel(const float* __restrict__ sim, const float* __restrict__ usage,
                                  float* __restrict__ rw, float* __restrict__ usage_out) {
    __shared__ float sm[16];
    int tid = threadIdx.x;
    int lane = tid & 63, wid = tid >> 6;
    float v0 = sim[tid], v1 = sim[tid + 1024], v2 = sim[tid + 2048], v3 = sim[tid + 3072];
    float m = fmaxf(fmaxf(v0, v1), fmaxf(v2, v3));
#pragma unroll
    for (int off = 32; off > 0; off >>= 1) m = fmaxf(m, __shfl_down(m, off));
    if (lane == 0) sm[wid] = m;
    __syncthreads();
    if (tid == 0) {
        float mm = sm[0];
        for (int i = 1; i < 16; ++i) mm = fmaxf(mm, sm[i]);
        sm[0] = mm;
    }
    __syncthreads();
    float mm = sm[0];
    float e0 = expf(v0 - mm), e1 = expf(v1 - mm), e2 = expf(v2 - mm), e3 = expf(v3 - mm);
    float s = e0 + e1 + e2 + e3;
#pragma unroll
    for (int off = 32; off > 0; off >>= 1) s += __shfl_down(s, off);
    __syncthreads();
    if (lane == 0) sm[wid] = s;
    __syncthreads();
    if (tid == 0) {
        float ss = 0.f;
        for (int i = 0; i < 16; ++i) ss += sm[i];
        sm[0] = ss;
    }
    __syncthreads();
    float inv = 1.f / sm[0];
    float r0 = e0 * inv, r1 = e1 * inv, r2 = e2 * inv, r3 = e3 * inv;
    rw[tid] = r0; rw[tid + 1024] = r1; rw[tid + 2048] = r2; rw[tid + 3072] = r3;
    usage_out[tid]        = usage[tid]        + r0;
    usage_out[tid + 1024] = usage[tid + 1024] + r1;
    usage_out[tid + 2048] = usage[tid + 2048] + r2;
    usage_out[tid + 3072] = usage[tid + 3072] + r3;
}

// Stage 1 of read_vec = rw @ memory: 64 blocks, each reduces 64 rows over all
// 1024 cols (256 thr x float4). partial[chunk][1024].
__global__ void readvec_partial_kernel(const float* __restrict__ memory,
                                       const float* __restrict__ rw,
                                       float* __restrict__ partial) {
    int t = threadIdx.x;   // 256
    int chunk = blockIdx.x; // 64
    const float4* mem4 = (const float4*)memory;
    float4 acc = make_float4(0.f, 0.f, 0.f, 0.f);
    int s0 = chunk * 64;
    for (int s = s0; s < s0 + 64; ++s) {
        float w = rw[s];
        float4 m = mem4[(size_t)s * 256 + t];
        acc.x = fmaf(w, m.x, acc.x);
        acc.y = fmaf(w, m.y, acc.y);
        acc.z = fmaf(w, m.z, acc.z);
        acc.w = fmaf(w, m.w, acc.w);
    }
    ((float4*)partial)[chunk * 256 + t] = acc;
}

// Stage 2: read_vec[c] = sum over 64 chunks; also build concat buffers.
// xcat = [x (2048) | read_vec (1024)], hvcat[2048:] = read_vec.
__global__ void readvec_reduce_kernel(const float* __restrict__ partial,
                                      const float* __restrict__ x,
                                      float* __restrict__ xcat, float* __restrict__ hvcat) {
    int c = threadIdx.x;  // 1024
    float s = 0.f;
    for (int k = 0; k < 64; ++k) s += partial[k * 1024 + c];
    xcat[2048 + c] = s;
    hvcat[2048 + c] = s;
    xcat[c] = x[c];
    xcat[1024 + c] = x[1024 + c];
}

// LSTM elementwise: 2048 elems. gates = gih + ghh + b_ih + b_hh (folded here).
__global__ void lstm_elem_kernel(const float* __restrict__ gih, const float* __restrict__ ghh,
                                 const float* __restrict__ b_ih, const float* __restrict__ b_hh,
                                 const float* __restrict__ c_prev,
                                 float* __restrict__ c_out, float* __restrict__ h_out,
                                 float* __restrict__ hvcat) {
    int t = blockIdx.x * blockDim.x + threadIdx.x;
    if (t >= HIDDEN_DIM) return;
    float gi = gih[t]        + ghh[t]        + b_ih[t]        + b_hh[t];
    float gf = gih[2048 + t] + ghh[2048 + t] + b_ih[2048 + t] + b_hh[2048 + t];
    float gg = gih[4096 + t] + ghh[4096 + t] + b_ih[4096 + t] + b_hh[4096 + t];
    float go = gih[6144 + t] + ghh[6144 + t] + b_ih[6144 + t] + b_hh[6144 + t];
    float ig = sigmoidf_(gi);
    float fg = sigmoidf_(gf);
    float g2 = tanhf(gg);
    float og = sigmoidf_(go);
    float c = fg * c_prev[t] + ig * g2;
    float h = og * tanhf(c);
    c_out[t] = c;
    h_out[t] = h;
    hvcat[t] = h;
}

// softmax over params[3072:7168] scaled by sigmoid(params[7168]) -> wv;
// also precompute erase = sigmoid(params[1024:2048]), add = tanh(params[2048:3072]).
__global__ void softmax_w_kernel(const float* __restrict__ params, float* __restrict__ wv,
                                 float* __restrict__ erase, float* __restrict__ addv) {
    __shared__ float sm[16];
    int tid = threadIdx.x;
    int lane = tid & 63, wid = tid >> 6;
    const float* logits = params + 3072;
    float v0 = logits[tid], v1 = logits[tid + 1024], v2 = logits[tid + 2048], v3 = logits[tid + 3072];
    float m = fmaxf(fmaxf(v0, v1), fmaxf(v2, v3));
#pragma unroll
    for (int off = 32; off > 0; off >>= 1) m = fmaxf(m, __shfl_down(m, off));
    if (lane == 0) sm[wid] = m;
    __syncthreads();
    if (tid == 0) {
        float mm = sm[0];
        for (int i = 1; i < 16; ++i) mm = fmaxf(mm, sm[i]);
        sm[0] = mm;
    }
    __syncthreads();
    float mm = sm[0];
    float e0 = expf(v0 - mm), e1 = expf(v1 - mm), e2 = expf(v2 - mm), e3 = expf(v3 - mm);
    float s = e0 + e1 + e2 + e3;
#pragma unroll
    for (int off = 32; off > 0; off >>= 1) s += __shfl_down(s, off);
    __syncthreads();
    if (lane == 0) sm[wid] = s;
    __syncthreads();
    if (tid == 0) {
        float ss = 0.f;
        for (int i = 0; i < 16; ++i) ss += sm[i];
        sm[0] = ss;
    }
    __syncthreads();
    float gate = sigmoidf_(params[7168]);
    float scale = gate / sm[0];
    wv[tid] = e0 * scale; wv[tid + 1024] = e1 * scale;
    wv[tid + 2048] = e2 * scale; wv[tid + 3072] = e3 * scale;
    erase[tid] = sigmoidf_(params[1024 + tid]);
    addv[tid]  = tanhf(params[2048 + tid]);
}

// new_memory[s,:] = mask(usage_new[s]) * memory[s,:] * (1 - w[s]*erase) + w[s]*add
__global__ void memupdate_kernel(const float* __restrict__ memory, const float* __restrict__ wv,
                                 const float* __restrict__ erase, const float* __restrict__ addv,
                                 const float* __restrict__ usage_new, float* __restrict__ newmem) {
    int s = blockIdx.x;   // 4096
    int t = threadIdx.x;  // 256 (float4 over 1024 cols)
    float w = wv[s];
    float mask = (usage_new[s] < 0.1f) ? 0.f : 1.f;
    float4 m = ((const float4*)memory)[(size_t)s * 256 + t];
    float4 e = ((const float4*)erase)[t];
    float4 a = ((const float4*)addv)[t];
    float4 r;
    r.x = mask * m.x * (1.f - w * e.x) + w * a.x;
    r.y = mask * m.y * (1.f - w * e.y) + w * a.y;
    r.z = mask * m.z * (1.f - w * e.z) + w * a.z;
    r.w = mask * m.w * (1.f - w * e.w) + w * a.w;
    ((float4*)newmem)[(size_t)s * 256 + t] = r;
}

extern "C" void kernel_launch(void* const* d_in, const int* in_sizes, int n_in,
                              void* d_out_, int out_size, void* d_ws, size_t ws_size,
                              hipStream_t stream) {
    const float* x      = (const float*)d_in[0];
    const float* h_prev = (const float*)d_in[1];
    const float* c_prev = (const float*)d_in[2];
    const float* memory = (const float*)d_in[3];
    const float* usage  = (const float*)d_in[4];
    const float* read_W = (const float*)d_in[5];
    const float* read_b = (const float*)d_in[6];
    const float* W_ih   = (const float*)d_in[7];
    const float* b_ih   = (const float*)d_in[8];
    const float* W_hh   = (const float*)d_in[9];
    const float* b_hh   = (const float*)d_in[10];
    const float* head_W = (const float*)d_in[11];
    const float* head_b = (const float*)d_in[12];
    const float* out_W  = (const float*)d_in[13];
    const float* out_b  = (const float*)d_in[14];

    float* d_out = (float*)d_out_;
    float* ws = (float*)d_ws;

    // workspace layout (floats)
    float* xcat    = ws + 0;      // 3072: [x | read_vec]
    float* hvcat   = ws + 3072;   // 3072: [h_new | read_vec]
    float* rk      = ws + 6144;   // 1024
    float* sim     = ws + 7168;   // 4096  (dead after readvec_partial)
    float* rw      = ws + 11264;  // 4096  (dead after readvec_partial)
    float* ghh     = ws + 7168;   // 8192: reuses sim|rw after they die
    float* gih     = ws + 15360;  // 8192
    float* params  = ws + 23552;  // 7169 (padded)
    float* wv      = ws + 30976;  // 4096
    float* erase   = ws + 35072;  // 1024
    float* addv    = ws + 36096;  // 1024
    float* partial = ws + 37120;  // 64*1024

    // output layout (floats): out | h_new | c_new | new_memory | usage_new
    float* out       = d_out;
    float* h_new     = d_out + 2048;
    float* c_new     = d_out + 4096;
    float* newmem    = d_out + 6144;
    float* usage_new = d_out + 6144 + (size_t)MEM_SLOTS * MEM_DIM;

    // 1. read_key = tanh(h_prev @ read_W.T + read_b)          (8 MB)
    gemv64_kernel<<<256, 256, 0, stream>>>(read_W, h_prev, read_b, rk, MEM_DIM, 512, 1);
    // 2. sim = memory @ read_key                              (16 MB)
    gemv64_kernel<<<1024, 256, 0, stream>>>(memory, rk, nullptr, sim, MEM_SLOTS, 256, 0);
    // 3. read_weights = softmax(sim); usage_new = usage + rw
    softmax_rw_kernel<<<1, 1024, 0, stream>>>(sim, usage, rw, usage_new);
    // 4-5. read_vec = rw @ memory (two-stage deterministic)   (16 MB, L3)
    readvec_partial_kernel<<<64, 256, 0, stream>>>(memory, rw, partial);
    readvec_reduce_kernel<<<1, 1024, 0, stream>>>(partial, x, xcat, hvcat);
    // 6. gih = xcat @ W_ih.T                                  (100.6 MB)
    gemv64_kernel<<<2048, 256, 0, stream>>>(W_ih, xcat, nullptr, gih, 4 * HIDDEN_DIM, 768, 0);
    // 7. ghh = h_prev @ W_hh.T  (sim/rw now dead -> reuse)    (67.1 MB)
    gemv64_kernel<<<2048, 256, 0, stream>>>(W_hh, h_prev, nullptr, ghh, 4 * HIDDEN_DIM, 512, 0);
    // 8. LSTM elementwise (biases folded) -> c_new, h_new
    lstm_elem_kernel<<<8, 256, 0, stream>>>(gih, ghh, b_ih, b_hh, c_prev, c_new, h_new, hvcat);
    // 9. params = h_new @ head_W.T + head_b                   (58.7 MB)
    gemv64_kernel<<<1793, 256, 0, stream>>>(head_W, h_new, head_b, params, 7169, 512, 0);
    // 10. w = softmax(logits)*sigmoid(gate); erase/add precompute
    softmax_w_kernel<<<1, 1024, 0, stream>>>(params, wv, erase, addv);
    // 11. memory update                                        (32 MB r+w)
    memupdate_kernel<<<4096, 256, 0, stream>>>(memory, wv, erase, addv, usage_new, newmem);
    // 12. out = hvcat @ out_W.T + out_b                        (24 MB)
    gemv64_kernel<<<512, 256, 0, stream>>>(out_W, hvcat, out_b, out, OUTPUT_DIM, 768, 0);
}

// Round 3
// 83.847 us; speedup vs baseline: 1.0701x; 1.0701x over previous
//
#include <hip/hip_runtime.h>
#include <math.h>

// ---------------------------------------------------------------------------
// PrefrontalCortex: memory-augmented LSTM cell, batch=1, fp32.
// All matmuls are GEMVs -> memory-bound.
// R3: gemv_t<K4,ACT> — 4 independent float4 loads in flight per wave,
// 4 accumulators, compile-time K4 (256/512/768) so outer loop fully unrolls.
// R1/R2 lesson: the naive 1-load-chain gemv is latency-bound at ~1.3-2.5 TB/s
// (VALUBusy 2.7%, VGPR=16 => ~2 loads in flight). This raises per-wave MLP 4x.
// ---------------------------------------------------------------------------

#define INPUT_DIM 2048
#define HIDDEN_DIM 2048
#define MEM_SLOTS 4096
#define MEM_DIM 1024
#define OUTPUT_DIM 2048

static __device__ __forceinline__ float sigmoidf_(float x) {
    return 1.0f / (1.0f + expf(-x));
}

// Wave-per-row GEMV with 4-way load batching.
// out[r] = act(dot(W[r,:], v) + bias[r]); K4 = K/4, must be multiple of 256.
template<int K4, int ACT>
__launch_bounds__(256)
__global__ void gemv_t(const float* __restrict__ W, const float* __restrict__ v,
                       const float* __restrict__ bias, float* __restrict__ out,
                       int rows) {
    int wave = (int)((blockIdx.x * blockDim.x + threadIdx.x) >> 6);
    int lane = threadIdx.x & 63;
    if (wave >= rows) return;
    const float4* __restrict__ Wr = (const float4*)W + (size_t)wave * (size_t)K4;
    const float4* __restrict__ v4 = (const float4*)v;
    float a0 = 0.f, a1 = 0.f, a2 = 0.f, a3 = 0.f;
#pragma unroll
    for (int i0 = 0; i0 < K4; i0 += 256) {
        int i = i0 + lane;
        // 8 loads issued before any use: 4 weight (HBM-streaming) + 4 vector
        // (L1/L2-hit). Keeps 4 KB of HBM traffic in flight per wave.
        float4 w0 = Wr[i];
        float4 w1 = Wr[i + 64];
        float4 w2 = Wr[i + 128];
        float4 w3 = Wr[i + 192];
        float4 x0 = v4[i];
        float4 x1 = v4[i + 64];
        float4 x2 = v4[i + 128];
        float4 x3 = v4[i + 192];
        a0 = fmaf(w0.x, x0.x, a0); a0 = fmaf(w0.y, x0.y, a0);
        a0 = fmaf(w0.z, x0.z, a0); a0 = fmaf(w0.w, x0.w, a0);
        a1 = fmaf(w1.x, x1.x, a1); a1 = fmaf(w1.y, x1.y, a1);
        a1 = fmaf(w1.z, x1.z, a1); a1 = fmaf(w1.w, x1.w, a1);
        a2 = fmaf(w2.x, x2.x, a2); a2 = fmaf(w2.y, x2.y, a2);
        a2 = fmaf(w2.z, x2.z, a2); a2 = fmaf(w2.w, x2.w, a2);
        a3 = fmaf(w3.x, x3.x, a3); a3 = fmaf(w3.y, x3.y, a3);
        a3 = fmaf(w3.z, x3.z, a3); a3 = fmaf(w3.w, x3.w, a3);
    }
    float acc = (a0 + a1) + (a2 + a3);
#pragma unroll
    for (int off = 32; off > 0; off >>= 1) acc += __shfl_down(acc, off);
    if (lane == 0) {
        float r = acc + (bias ? bias[wave] : 0.f);
        if (ACT == 1) r = tanhf(r);
        out[wave] = r;
    }
}

// softmax over sim[0:4096] -> rw; usage_out = usage + rw.  One block, 1024 thr.
__global__ void softmax_rw_kernel(const float* __restrict__ sim, const float* __restrict__ usage,
                                  float* __restrict__ rw, float* __restrict__ usage_out) {
    __shared__ float sm[16];
    int tid = threadIdx.x;
    int lane = tid & 63, wid = tid >> 6;
    float v0 = sim[tid], v1 = sim[tid + 1024], v2 = sim[tid + 2048], v3 = sim[tid + 3072];
    float m = fmaxf(fmaxf(v0, v1), fmaxf(v2, v3));
#pragma unroll
    for (int off = 32; off > 0; off >>= 1) m = fmaxf(m, __shfl_down(m, off));
    if (lane == 0) sm[wid] = m;
    __syncthreads();
    if (tid == 0) {
        float mm = sm[0];
        for (int i = 1; i < 16; ++i) mm = fmaxf(mm, sm[i]);
        sm[0] = mm;
    }
    __syncthreads();
    float mm = sm[0];
    float e0 = expf(v0 - mm), e1 = expf(v1 - mm), e2 = expf(v2 - mm), e3 = expf(v3 - mm);
    float s = e0 + e1 + e2 + e3;
#pragma unroll
    for (int off = 32; off > 0; off >>= 1) s += __shfl_down(s, off);
    __syncthreads();
    if (lane == 0) sm[wid] = s;
    __syncthreads();
    if (tid == 0) {
        float ss = 0.f;
        for (int i = 0; i < 16; ++i) ss += sm[i];
        sm[0] = ss;
    }
    __syncthreads();
    float inv = 1.f / sm[0];
    float r0 = e0 * inv, r1 = e1 * inv, r2 = e2 * inv, r3 = e3 * inv;
    rw[tid] = r0; rw[tid + 1024] = r1; rw[tid + 2048] = r2; rw[tid + 3072] = r3;
    usage_out[tid]        = usage[tid]        + r0;
    usage_out[tid + 1024] = usage[tid + 1024] + r1;
    usage_out[tid + 2048] = usage[tid + 2048] + r2;
    usage_out[tid + 3072] = usage[tid + 3072] + r3;
}

// Stage 1 of read_vec = rw @ memory: 64 blocks, each reduces 64 rows over all
// 1024 cols (256 thr x float4). partial[chunk][1024].
__global__ void readvec_partial_kernel(const float* __restrict__ memory,
                                       const float* __restrict__ rw,
                                       float* __restrict__ partial) {
    int t = threadIdx.x;   // 256
    int chunk = blockIdx.x; // 64
    const float4* mem4 = (const float4*)memory;
    float4 acc = make_float4(0.f, 0.f, 0.f, 0.f);
    int s0 = chunk * 64;
    for (int s = s0; s < s0 + 64; ++s) {
        float w = rw[s];
        float4 m = mem4[(size_t)s * 256 + t];
        acc.x = fmaf(w, m.x, acc.x);
        acc.y = fmaf(w, m.y, acc.y);
        acc.z = fmaf(w, m.z, acc.z);
        acc.w = fmaf(w, m.w, acc.w);
    }
    ((float4*)partial)[chunk * 256 + t] = acc;
}

// Stage 2: read_vec[c] = sum over 64 chunks; also build concat buffers.
// xcat = [x (2048) | read_vec (1024)], hvcat[2048:] = read_vec.
__global__ void readvec_reduce_kernel(const float* __restrict__ partial,
                                      const float* __restrict__ x,
                                      float* __restrict__ xcat, float* __restrict__ hvcat) {
    int c = threadIdx.x;  // 1024
    float s = 0.f;
    for (int k = 0; k < 64; ++k) s += partial[k * 1024 + c];
    xcat[2048 + c] = s;
    hvcat[2048 + c] = s;
    xcat[c] = x[c];
    xcat[1024 + c] = x[1024 + c];
}

// LSTM elementwise: 2048 elems. gates = gih + ghh + b_ih + b_hh (folded here).
__global__ void lstm_elem_kernel(const float* __restrict__ gih, const float* __restrict__ ghh,
                                 const float* __restrict__ b_ih, const float* __restrict__ b_hh,
                                 const float* __restrict__ c_prev,
                                 float* __restrict__ c_out, float* __restrict__ h_out,
                                 float* __restrict__ hvcat) {
    int t = blockIdx.x * blockDim.x + threadIdx.x;
    if (t >= HIDDEN_DIM) return;
    float gi = gih[t]        + ghh[t]        + b_ih[t]        + b_hh[t];
    float gf = gih[2048 + t] + ghh[2048 + t] + b_ih[2048 + t] + b_hh[2048 + t];
    float gg = gih[4096 + t] + ghh[4096 + t] + b_ih[4096 + t] + b_hh[4096 + t];
    float go = gih[6144 + t] + ghh[6144 + t] + b_ih[6144 + t] + b_hh[6144 + t];
    float ig = sigmoidf_(gi);
    float fg = sigmoidf_(gf);
    float g2 = tanhf(gg);
    float og = sigmoidf_(go);
    float c = fg * c_prev[t] + ig * g2;
    float h = og * tanhf(c);
    c_out[t] = c;
    h_out[t] = h;
    hvcat[t] = h;
}

// softmax over params[3072:7168] scaled by sigmoid(params[7168]) -> wv;
// also precompute erase = sigmoid(params[1024:2048]), add = tanh(params[2048:3072]).
__global__ void softmax_w_kernel(const float* __restrict__ params, float* __restrict__ wv,
                                 float* __restrict__ erase, float* __restrict__ addv) {
    __shared__ float sm[16];
    int tid = threadIdx.x;
    int lane = tid & 63, wid = tid >> 6;
    const float* logits = params + 3072;
    float v0 = logits[tid], v1 = logits[tid + 1024], v2 = logits[tid + 2048], v3 = logits[tid + 3072];
    float m = fmaxf(fmaxf(v0, v1), fmaxf(v2, v3));
#pragma unroll
    for (int off = 32; off > 0; off >>= 1) m = fmaxf(m, __shfl_down(m, off));
    if (lane == 0) sm[wid] = m;
    __syncthreads();
    if (tid == 0) {
        float mm = sm[0];
        for (int i = 1; i < 16; ++i) mm = fmaxf(mm, sm[i]);
        sm[0] = mm;
    }
    __syncthreads();
    float mm = sm[0];
    float e0 = expf(v0 - mm), e1 = expf(v1 - mm), e2 = expf(v2 - mm), e3 = expf(v3 - mm);
    float s = e0 + e1 + e2 + e3;
#pragma unroll
    for (int off = 32; off > 0; off >>= 1) s += __shfl_down(s, off);
    __syncthreads();
    if (lane == 0) sm[wid] = s;
    __syncthreads();
    if (tid == 0) {
        float ss = 0.f;
        for (int i = 0; i < 16; ++i) ss += sm[i];
        sm[0] = ss;
    }
    __syncthreads();
    float gate = sigmoidf_(params[7168]);
    float scale = gate / sm[0];
    wv[tid] = e0 * scale; wv[tid + 1024] = e1 * scale;
    wv[tid + 2048] = e2 * scale; wv[tid + 3072] = e3 * scale;
    erase[tid] = sigmoidf_(params[1024 + tid]);
    addv[tid]  = tanhf(params[2048 + tid]);
}

// new_memory[s,:] = mask(usage_new[s]) * memory[s,:] * (1 - w[s]*erase) + w[s]*add
__global__ void memupdate_kernel(const float* __restrict__ memory, const float* __restrict__ wv,
                                 const float* __restrict__ erase, const float* __restrict__ addv,
                                 const float* __restrict__ usage_new, float* __restrict__ newmem) {
    int s = blockIdx.x;   // 4096
    int t = threadIdx.x;  // 256 (float4 over 1024 cols)
    float w = wv[s];
    float mask = (usage_new[s] < 0.1f) ? 0.f : 1.f;
    float4 m = ((const float4*)memory)[(size_t)s * 256 + t];
    float4 e = ((const float4*)erase)[t];
    float4 a = ((const float4*)addv)[t];
    float4 r;
    r.x = mask * m.x * (1.f - w * e.x) + w * a.x;
    r.y = mask * m.y * (1.f - w * e.y) + w * a.y;
    r.z = mask * m.z * (1.f - w * e.z) + w * a.z;
    r.w = mask * m.w * (1.f - w * e.w) + w * a.w;
    ((float4*)newmem)[(size_t)s * 256 + t] = r;
}

extern "C" void kernel_launch(void* const* d_in, const int* in_sizes, int n_in,
                              void* d_out_, int out_size, void* d_ws, size_t ws_size,
                              hipStream_t stream) {
    const float* x      = (const float*)d_in[0];
    const float* h_prev = (const float*)d_in[1];
    const float* c_prev = (const float*)d_in[2];
    const float* memory = (const float*)d_in[3];
    const float* usage  = (const float*)d_in[4];
    const float* read_W = (const float*)d_in[5];
    const float* read_b = (const float*)d_in[6];
    const float* W_ih   = (const float*)d_in[7];
    const float* b_ih   = (const float*)d_in[8];
    const float* W_hh   = (const float*)d_in[9];
    const float* b_hh   = (const float*)d_in[10];
    const float* head_W = (const float*)d_in[11];
    const float* head_b = (const float*)d_in[12];
    const float* out_W  = (const float*)d_in[13];
    const float* out_b  = (const float*)d_in[14];

    float* d_out = (float*)d_out_;
    float* ws = (float*)d_ws;

    // workspace layout (floats)
    float* xcat    = ws + 0;      // 3072: [x | read_vec]
    float* hvcat   = ws + 3072;   // 3072: [h_new | read_vec]
    float* rk      = ws + 6144;   // 1024
    float* sim     = ws + 7168;   // 4096  (dead after readvec_partial)
    float* rw      = ws + 11264;  // 4096  (dead after readvec_partial)
    float* ghh     = ws + 7168;   // 8192: reuses sim|rw after they die
    float* gih     = ws + 15360;  // 8192
    float* params  = ws + 23552;  // 7169 (padded)
    float* wv      = ws + 30976;  // 4096
    float* erase   = ws + 35072;  // 1024
    float* addv    = ws + 36096;  // 1024
    float* partial = ws + 37120;  // 64*1024

    // output layout (floats): out | h_new | c_new | new_memory | usage_new
    float* out       = d_out;
    float* h_new     = d_out + 2048;
    float* c_new     = d_out + 4096;
    float* newmem    = d_out + 6144;
    float* usage_new = d_out + 6144 + (size_t)MEM_SLOTS * MEM_DIM;

    // 1. read_key = tanh(h_prev @ read_W.T + read_b)          (8 MB)
    gemv_t<512, 1><<<256, 256, 0, stream>>>(read_W, h_prev, read_b, rk, MEM_DIM);
    // 2. sim = memory @ read_key                              (16 MB)
    gemv_t<256, 0><<<1024, 256, 0, stream>>>(memory, rk, nullptr, sim, MEM_SLOTS);
    // 3. read_weights = softmax(sim); usage_new = usage + rw
    softmax_rw_kernel<<<1, 1024, 0, stream>>>(sim, usage, rw, usage_new);
    // 4-5. read_vec = rw @ memory (two-stage deterministic)   (16 MB, L3)
    readvec_partial_kernel<<<64, 256, 0, stream>>>(memory, rw, partial);
    readvec_reduce_kernel<<<1, 1024, 0, stream>>>(partial, x, xcat, hvcat);
    // 6. gih = xcat @ W_ih.T                                  (100.6 MB)
    gemv_t<768, 0><<<2048, 256, 0, stream>>>(W_ih, xcat, nullptr, gih, 4 * HIDDEN_DIM);
    // 7. ghh = h_prev @ W_hh.T  (sim/rw now dead -> reuse)    (67.1 MB)
    gemv_t<512, 0><<<2048, 256, 0, stream>>>(W_hh, h_prev, nullptr, ghh, 4 * HIDDEN_DIM);
    // 8. LSTM elementwise (biases folded) -> c_new, h_new
    lstm_elem_kernel<<<8, 256, 0, stream>>>(gih, ghh, b_ih, b_hh, c_prev, c_new, h_new, hvcat);
    // 9. params = h_new @ head_W.T + head_b                   (58.7 MB)
    gemv_t<512, 0><<<1793, 256, 0, stream>>>(head_W, h_new, head_b, params, 7169);
    // 10. w = softmax(logits)*sigmoid(gate); erase/add precompute
    softmax_w_kernel<<<1, 1024, 0, stream>>>(params, wv, erase, addv);
    // 11. memory update                                        (32 MB r+w)
    memupdate_kernel<<<4096, 256, 0, stream>>>(memory, wv, erase, addv, usage_new, newmem);
    // 12. out = hvcat @ out_W.T + out_b                        (24 MB)
    gemv_t<768, 0><<<512, 256, 0, stream>>>(out_W, hvcat, out_b, out, OUTPUT_DIM);
}

// Round 5
// 80.723 us; speedup vs baseline: 1.1116x; 1.0387x over previous
//
#include <hip/hip_runtime.h>
#include <math.h>

// ---------------------------------------------------------------------------
// PrefrontalCortex: memory-augmented LSTM cell, batch=1, fp32.
// R5 = R4 with the compile fix: __builtin_nontemporal_load needs a native
// clang vector type, not HIP_vector_type<float,4>. Use ext_vector_type(4).
// R4 rationale:
//  (1) nontemporal loads for the two L3-thrashing matrices (W_ih, W_hh):
//      bypasses L1 allocation (tests the per-CU read-miss-concurrency cap)
//      and keeps them OUT of L3 so head_W/out_W/memory/read_W (~107 MB) stay
//      L3-resident across graph replays.
//  (2) head GEMV skips rows [0,1024): params[0:1024] is never used. -8.4 MB.
// Model: cold-HBM pure-read ≈ 3.1 TB/s (miss-concurrency-limited), writes
// ~7 TB/s, L3-hit reads fast. gih+ghh ≈ 55 us @ 3.05 TB/s is the target.
// ---------------------------------------------------------------------------

#define INPUT_DIM 2048
#define HIDDEN_DIM 2048
#define MEM_SLOTS 4096
#define MEM_DIM 1024
#define OUTPUT_DIM 2048

typedef float floatx4 __attribute__((ext_vector_type(4)));

static __device__ __forceinline__ float sigmoidf_(float x) {
    return 1.0f / (1.0f + expf(-x));
}

template<bool NT>
static __device__ __forceinline__ floatx4 ld4_(const float4* p) {
    if constexpr (NT) {
        return __builtin_nontemporal_load((const floatx4*)p);
    } else {
        return *(const floatx4*)p;
    }
}

// Wave-per-row GEMV with 4-way load batching.
// out[r] = act(dot(W[r,:], v) + bias[r]); K4 = K/4, must be multiple of 256.
// NT: nontemporal weight loads (bypass cache allocation).
template<int K4, int ACT, bool NT>
__launch_bounds__(256)
__global__ void gemv_t(const float* __restrict__ W, const float* __restrict__ v,
                       const float* __restrict__ bias, float* __restrict__ out,
                       int rows) {
    int wave = (int)((blockIdx.x * blockDim.x + threadIdx.x) >> 6);
    int lane = threadIdx.x & 63;
    if (wave >= rows) return;
    const float4* __restrict__ Wr = (const float4*)W + (size_t)wave * (size_t)K4;
    const float4* __restrict__ v4 = (const float4*)v;
    float a0 = 0.f, a1 = 0.f, a2 = 0.f, a3 = 0.f;
#pragma unroll
    for (int i0 = 0; i0 < K4; i0 += 256) {
        int i = i0 + lane;
        floatx4 w0 = ld4_<NT>(&Wr[i]);
        floatx4 w1 = ld4_<NT>(&Wr[i + 64]);
        floatx4 w2 = ld4_<NT>(&Wr[i + 128]);
        floatx4 w3 = ld4_<NT>(&Wr[i + 192]);
        floatx4 x0 = ld4_<false>(&v4[i]);
        floatx4 x1 = ld4_<false>(&v4[i + 64]);
        floatx4 x2 = ld4_<false>(&v4[i + 128]);
        floatx4 x3 = ld4_<false>(&v4[i + 192]);
        a0 = fmaf(w0.x, x0.x, a0); a0 = fmaf(w0.y, x0.y, a0);
        a0 = fmaf(w0.z, x0.z, a0); a0 = fmaf(w0.w, x0.w, a0);
        a1 = fmaf(w1.x, x1.x, a1); a1 = fmaf(w1.y, x1.y, a1);
        a1 = fmaf(w1.z, x1.z, a1); a1 = fmaf(w1.w, x1.w, a1);
        a2 = fmaf(w2.x, x2.x, a2); a2 = fmaf(w2.y, x2.y, a2);
        a2 = fmaf(w2.z, x2.z, a2); a2 = fmaf(w2.w, x2.w, a2);
        a3 = fmaf(w3.x, x3.x, a3); a3 = fmaf(w3.y, x3.y, a3);
        a3 = fmaf(w3.z, x3.z, a3); a3 = fmaf(w3.w, x3.w, a3);
    }
    float acc = (a0 + a1) + (a2 + a3);
#pragma unroll
    for (int off = 32; off > 0; off >>= 1) acc += __shfl_down(acc, off);
    if (lane == 0) {
        float r = acc + (bias ? bias[wave] : 0.f);
        if (ACT == 1) r = tanhf(r);
        out[wave] = r;
    }
}

// softmax over sim[0:4096] -> rw; usage_out = usage + rw.  One block, 1024 thr.
__global__ void softmax_rw_kernel(const float* __restrict__ sim, const float* __restrict__ usage,
                                  float* __restrict__ rw, float* __restrict__ usage_out) {
    __shared__ float sm[16];
    int tid = threadIdx.x;
    int lane = tid & 63, wid = tid >> 6;
    float v0 = sim[tid], v1 = sim[tid + 1024], v2 = sim[tid + 2048], v3 = sim[tid + 3072];
    float m = fmaxf(fmaxf(v0, v1), fmaxf(v2, v3));
#pragma unroll
    for (int off = 32; off > 0; off >>= 1) m = fmaxf(m, __shfl_down(m, off));
    if (lane == 0) sm[wid] = m;
    __syncthreads();
    if (tid == 0) {
        float mm = sm[0];
        for (int i = 1; i < 16; ++i) mm = fmaxf(mm, sm[i]);
        sm[0] = mm;
    }
    __syncthreads();
    float mm = sm[0];
    float e0 = expf(v0 - mm), e1 = expf(v1 - mm), e2 = expf(v2 - mm), e3 = expf(v3 - mm);
    float s = e0 + e1 + e2 + e3;
#pragma unroll
    for (int off = 32; off > 0; off >>= 1) s += __shfl_down(s, off);
    __syncthreads();
    if (lane == 0) sm[wid] = s;
    __syncthreads();
    if (tid == 0) {
        float ss = 0.f;
        for (int i = 0; i < 16; ++i) ss += sm[i];
        sm[0] = ss;
    }
    __syncthreads();
    float inv = 1.f / sm[0];
    float r0 = e0 * inv, r1 = e1 * inv, r2 = e2 * inv, r3 = e3 * inv;
    rw[tid] = r0; rw[tid + 1024] = r1; rw[tid + 2048] = r2; rw[tid + 3072] = r3;
    usage_out[tid]        = usage[tid]        + r0;
    usage_out[tid + 1024] = usage[tid + 1024] + r1;
    usage_out[tid + 2048] = usage[tid + 2048] + r2;
    usage_out[tid + 3072] = usage[tid + 3072] + r3;
}

// Stage 1 of read_vec = rw @ memory: 64 blocks, each reduces 64 rows over all
// 1024 cols (256 thr x float4). partial[chunk][1024].
__global__ void readvec_partial_kernel(const float* __restrict__ memory,
                                       const float* __restrict__ rw,
                                       float* __restrict__ partial) {
    int t = threadIdx.x;   // 256
    int chunk = blockIdx.x; // 64
    const float4* mem4 = (const float4*)memory;
    float4 acc = make_float4(0.f, 0.f, 0.f, 0.f);
    int s0 = chunk * 64;
    for (int s = s0; s < s0 + 64; ++s) {
        float w = rw[s];
        float4 m = mem4[(size_t)s * 256 + t];
        acc.x = fmaf(w, m.x, acc.x);
        acc.y = fmaf(w, m.y, acc.y);
        acc.z = fmaf(w, m.z, acc.z);
        acc.w = fmaf(w, m.w, acc.w);
    }
    ((float4*)partial)[chunk * 256 + t] = acc;
}

// Stage 2: read_vec[c] = sum over 64 chunks; also build concat buffers.
// xcat = [x (2048) | read_vec (1024)], hvcat[2048:] = read_vec.
__global__ void readvec_reduce_kernel(const float* __restrict__ partial,
                                      const float* __restrict__ x,
                                      float* __restrict__ xcat, float* __restrict__ hvcat) {
    int c = threadIdx.x;  // 1024
    float s = 0.f;
    for (int k = 0; k < 64; ++k) s += partial[k * 1024 + c];
    xcat[2048 + c] = s;
    hvcat[2048 + c] = s;
    xcat[c] = x[c];
    xcat[1024 + c] = x[1024 + c];
}

// LSTM elementwise: 2048 elems. gates = gih + ghh + b_ih + b_hh (folded here).
__global__ void lstm_elem_kernel(const float* __restrict__ gih, const float* __restrict__ ghh,
                                 const float* __restrict__ b_ih, const float* __restrict__ b_hh,
                                 const float* __restrict__ c_prev,
                                 float* __restrict__ c_out, float* __restrict__ h_out,
                                 float* __restrict__ hvcat) {
    int t = blockIdx.x * blockDim.x + threadIdx.x;
    if (t >= HIDDEN_DIM) return;
    float gi = gih[t]        + ghh[t]        + b_ih[t]        + b_hh[t];
    float gf = gih[2048 + t] + ghh[2048 + t] + b_ih[2048 + t] + b_hh[2048 + t];
    float gg = gih[4096 + t] + ghh[4096 + t] + b_ih[4096 + t] + b_hh[4096 + t];
    float go = gih[6144 + t] + ghh[6144 + t] + b_ih[6144 + t] + b_hh[6144 + t];
    float ig = sigmoidf_(gi);
    float fg = sigmoidf_(gf);
    float g2 = tanhf(gg);
    float og = sigmoidf_(go);
    float c = fg * c_prev[t] + ig * g2;
    float h = og * tanhf(c);
    c_out[t] = c;
    h_out[t] = h;
    hvcat[t] = h;
}

// softmax over params[3072:7168] scaled by sigmoid(params[7168]) -> wv;
// also precompute erase = sigmoid(params[1024:2048]), add = tanh(params[2048:3072]).
__global__ void softmax_w_kernel(const float* __restrict__ params, float* __restrict__ wv,
                                 float* __restrict__ erase, float* __restrict__ addv) {
    __shared__ float sm[16];
    int tid = threadIdx.x;
    int lane = tid & 63, wid = tid >> 6;
    const float* logits = params + 3072;
    float v0 = logits[tid], v1 = logits[tid + 1024], v2 = logits[tid + 2048], v3 = logits[tid + 3072];
    float m = fmaxf(fmaxf(v0, v1), fmaxf(v2, v3));
#pragma unroll
    for (int off = 32; off > 0; off >>= 1) m = fmaxf(m, __shfl_down(m, off));
    if (lane == 0) sm[wid] = m;
    __syncthreads();
    if (tid == 0) {
        float mm = sm[0];
        for (int i = 1; i < 16; ++i) mm = fmaxf(mm, sm[i]);
        sm[0] = mm;
    }
    __syncthreads();
    float mm = sm[0];
    float e0 = expf(v0 - mm), e1 = expf(v1 - mm), e2 = expf(v2 - mm), e3 = expf(v3 - mm);
    float s = e0 + e1 + e2 + e3;
#pragma unroll
    for (int off = 32; off > 0; off >>= 1) s += __shfl_down(s, off);
    __syncthreads();
    if (lane == 0) sm[wid] = s;
    __syncthreads();
    if (tid == 0) {
        float ss = 0.f;
        for (int i = 0; i < 16; ++i) ss += sm[i];
        sm[0] = ss;
    }
    __syncthreads();
    float gate = sigmoidf_(params[7168]);
    float scale = gate / sm[0];
    wv[tid] = e0 * scale; wv[tid + 1024] = e1 * scale;
    wv[tid + 2048] = e2 * scale; wv[tid + 3072] = e3 * scale;
    erase[tid] = sigmoidf_(params[1024 + tid]);
    addv[tid]  = tanhf(params[2048 + tid]);
}

// new_memory[s,:] = mask(usage_new[s]) * memory[s,:] * (1 - w[s]*erase) + w[s]*add
__global__ void memupdate_kernel(const float* __restrict__ memory, const float* __restrict__ wv,
                                 const float* __restrict__ erase, const float* __restrict__ addv,
                                 const float* __restrict__ usage_new, float* __restrict__ newmem) {
    int s = blockIdx.x;   // 4096
    int t = threadIdx.x;  // 256 (float4 over 1024 cols)
    float w = wv[s];
    float mask = (usage_new[s] < 0.1f) ? 0.f : 1.f;
    float4 m = ((const float4*)memory)[(size_t)s * 256 + t];
    float4 e = ((const float4*)erase)[t];
    float4 a = ((const float4*)addv)[t];
    float4 r;
    r.x = mask * m.x * (1.f - w * e.x) + w * a.x;
    r.y = mask * m.y * (1.f - w * e.y) + w * a.y;
    r.z = mask * m.z * (1.f - w * e.z) + w * a.z;
    r.w = mask * m.w * (1.f - w * e.w) + w * a.w;
    ((float4*)newmem)[(size_t)s * 256 + t] = r;
}

extern "C" void kernel_launch(void* const* d_in, const int* in_sizes, int n_in,
                              void* d_out_, int out_size, void* d_ws, size_t ws_size,
                              hipStream_t stream) {
    const float* x      = (const float*)d_in[0];
    const float* h_prev = (const float*)d_in[1];
    const float* c_prev = (const float*)d_in[2];
    const float* memory = (const float*)d_in[3];
    const float* usage  = (const float*)d_in[4];
    const float* read_W = (const float*)d_in[5];
    const float* read_b = (const float*)d_in[6];
    const float* W_ih   = (const float*)d_in[7];
    const float* b_ih   = (const float*)d_in[8];
    const float* W_hh   = (const float*)d_in[9];
    const float* b_hh   = (const float*)d_in[10];
    const float* head_W = (const float*)d_in[11];
    const float* head_b = (const float*)d_in[12];
    const float* out_W  = (const float*)d_in[13];
    const float* out_b  = (const float*)d_in[14];

    float* d_out = (float*)d_out_;
    float* ws = (float*)d_ws;

    // workspace layout (floats)
    float* xcat    = ws + 0;      // 3072: [x | read_vec]
    float* hvcat   = ws + 3072;   // 3072: [h_new | read_vec]
    float* rk      = ws + 6144;   // 1024
    float* sim     = ws + 7168;   // 4096  (dead after readvec_partial)
    float* rw      = ws + 11264;  // 4096  (dead after readvec_partial)
    float* ghh     = ws + 7168;   // 8192: reuses sim|rw after they die
    float* gih     = ws + 15360;  // 8192
    float* params  = ws + 23552;  // 7169 (rows [0,1024) never written/read)
    float* wv      = ws + 30976;  // 4096
    float* erase   = ws + 35072;  // 1024
    float* addv    = ws + 36096;  // 1024
    float* partial = ws + 37120;  // 64*1024

    // output layout (floats): out | h_new | c_new | new_memory | usage_new
    float* out       = d_out;
    float* h_new     = d_out + 2048;
    float* c_new     = d_out + 4096;
    float* newmem    = d_out + 6144;
    float* usage_new = d_out + 6144 + (size_t)MEM_SLOTS * MEM_DIM;

    // 1. read_key = tanh(h_prev @ read_W.T + read_b)          (8 MB, L3)
    gemv_t<512, 1, false><<<256, 256, 0, stream>>>(read_W, h_prev, read_b, rk, MEM_DIM);
    // 2. sim = memory @ read_key                              (16 MB, L3)
    gemv_t<256, 0, false><<<1024, 256, 0, stream>>>(memory, rk, nullptr, sim, MEM_SLOTS);
    // 3. read_weights = softmax(sim); usage_new = usage + rw
    softmax_rw_kernel<<<1, 1024, 0, stream>>>(sim, usage, rw, usage_new);
    // 4-5. read_vec = rw @ memory (two-stage deterministic)   (16 MB, L3)
    readvec_partial_kernel<<<64, 256, 0, stream>>>(memory, rw, partial);
    readvec_reduce_kernel<<<1, 1024, 0, stream>>>(partial, x, xcat, hvcat);
    // 6. gih = xcat @ W_ih.T                        (100.6 MB, NT stream)
    gemv_t<768, 0, true><<<2048, 256, 0, stream>>>(W_ih, xcat, nullptr, gih, 4 * HIDDEN_DIM);
    // 7. ghh = h_prev @ W_hh.T                      (67.1 MB, NT stream)
    gemv_t<512, 0, true><<<2048, 256, 0, stream>>>(W_hh, h_prev, nullptr, ghh, 4 * HIDDEN_DIM);
    // 8. LSTM elementwise (biases folded) -> c_new, h_new
    lstm_elem_kernel<<<8, 256, 0, stream>>>(gih, ghh, b_ih, b_hh, c_prev, c_new, h_new, hvcat);
    // 9. params[1024:7169] = h_new @ head_W[1024:].T + head_b[1024:]
    //    rows [0,1024) of head_W are provably unused -> skipped (-8.4 MB).
    gemv_t<512, 0, false><<<1537, 256, 0, stream>>>(
        head_W + (size_t)1024 * HIDDEN_DIM, h_new, head_b + 1024, params + 1024, 7169 - 1024);
    // 10. w = softmax(logits)*sigmoid(gate); erase/add precompute
    softmax_w_kernel<<<1, 1024, 0, stream>>>(params, wv, erase, addv);
    // 11. memory update                                        (16r L3 + 16w)
    memupdate_kernel<<<4096, 256, 0, stream>>>(memory, wv, erase, addv, usage_new, newmem);
    // 12. out = hvcat @ out_W.T + out_b                        (24 MB, L3)
    gemv_t<768, 0, false><<<512, 256, 0, stream>>>(out_W, hvcat, out_b, out, OUTPUT_DIM);
}